// Round 16
// baseline (50.181 us; speedup 1.0000x reference)
//
#include <hip/hip_runtime.h>

#define BATCH 8
#define CIN   64
#define COUT  64
#define LEN   16384
#define KS    5
#define PADW  2
#define LP    (LEN + 2*PADW)
#define TTB   128            // cols per block (2 subtiles of 64)
#define XROWS 168            // single staged window: rows xp[S0 .. S0+167]
#define XM    14             // S0 = T0 - 14  =>  x index of row r = T0 - 16 + r (16B aligned)

typedef __attribute__((ext_vector_type(8)))  short short8;
typedef __attribute__((ext_vector_type(4)))  float f32x4;
typedef __attribute__((ext_vector_type(8)))  unsigned short ushort8;

__device__ __forceinline__ unsigned short bf16r(float f) {
    unsigned u = __builtin_bit_cast(unsigned, f);
    u += 0x7FFF + ((u >> 16) & 1);          // RNE
    return (unsigned short)(u >> 16);
}
__device__ __forceinline__ int reflmap(int s) {  // padded idx -> x idx
    return (s < PADW) ? (PADW - s) : ((s < LEN + PADW) ? (s - PADW) : (2*LEN - s));
}

// W (f32 [o][c][k]) -> bf16 A-frags for mfma_f32_16x16x32_bf16, K k-major
// (ck' = ktap*64 + c).  wf[((ot*10 + kk)*64 + lane)*8 + e]
__global__ void wfrag_kernel(const float* __restrict__ w, unsigned short* __restrict__ wf) {
    int el = blockIdx.x * 256 + threadIdx.x;          // 20480 total
    int e    = el & 7;
    int lane = (el >> 3) & 63;
    int kk   = (el >> 9) % 10;
    int ot   = el / 5120;
    int o    = ot * 16 + (lane & 15);
    int kg   = kk * 32 + ((lane >> 4) << 3) + e;      // ck' 0..319
    int ktap = kg >> 6;
    int c    = kg & 63;
    wf[el] = bf16r(w[(o * 64 + c) * 5 + ktap]);
}

__global__ __launch_bounds__(256, 4) void deform_mfma_kernel(
    const float* __restrict__ x, const float* __restrict__ offs,
    const unsigned short* __restrict__ wf, const float* __restrict__ bias,
    float* __restrict__ out)
{
    __shared__ __align__(16) unsigned short xt[XROWS * 64];   // 21504 B

    const int tid = threadIdx.x;
    const int bid = blockIdx.x;
    const int bt  = (bid & 7) * 128 + (bid >> 3);    // XCD swizzle (1024 = 8*128)
    const int b   = bt >> 7;
    const int T0  = (bt & 127) * TTB;
    const int w   = tid >> 6;
    const int lane = tid & 63;
    const int pl  = lane & 15;
    const int s   = lane >> 4;
    const int S0  = T0 - XM;

    const float* xb0 = x + (size_t)b * CIN * LEN;
    const unsigned short* wfl = wf + (size_t)lane * 8;

    // ---- preload offsets for both subtiles ----
    float of[2][KS];
    #pragma unroll
    for (int it = 0; it < 2; ++it) {
        const int tc = T0 + it * 64 + w * 16 + pl;
        #pragma unroll
        for (int k = 0; k < KS; ++k)
            of[it][k] = offs[((size_t)(b * LEN + tc)) * KS + k];
    }

    // ---- stage window: xt[r][c] = bf16(xp[S0+r]) = bf16(x[T0-16+r]), swizzled ----
    if (T0 >= 16 && T0 + 152 <= LEN) {               // fast: x idx = T0-16+r
        const float* src0 = xb0 + (T0 - 16);
        #pragma unroll
        for (int rep = 0; rep < 6; ++rep) {
            int task = rep * 256 + tid;              // 1344 = 32 ch-pairs x 42 row-quads
            if (task < 1344) {
                int c2 = task / 42, q = task - c2 * 42;
                const float* p0 = src0 + (size_t)(2 * c2) * LEN + 4 * q;
                float4 va = *(const float4*)p0;
                float4 vb = *(const float4*)(p0 + LEN);
                #pragma unroll
                for (int i = 0; i < 4; ++i) {
                    int r = 4 * q + i;
                    float a = (i==0)?va.x:(i==1)?va.y:(i==2)?va.z:va.w;
                    float bb = (i==0)?vb.x:(i==1)?vb.y:(i==2)?vb.z:vb.w;
                    unsigned pk = (unsigned)bf16r(a) | ((unsigned)bf16r(bb) << 16);
                    *(unsigned*)((char*)xt + r * 128 + ((4 * c2) ^ ((r & 7) << 4))) = pk;
                }
            }
        }
    } else {                                          // edge tiles (16 of 1024)
        #pragma unroll
        for (int rep = 0; rep < 42; ++rep) {
            int idx = rep * 256 + tid;               // 0..10751
            int r = idx >> 6, c = idx & 63;
            int sp = min(max(S0 + r, 0), LP - 1);
            *(unsigned short*)((char*)xt + r * 128 + ((2 * c) ^ ((r & 7) << 4))) =
                bf16r(xb0[(size_t)c * LEN + reflmap(sp)]);
        }
    }
    __syncthreads();

#define LERPP(pk, j, w0, w1, f)                                                \
    {                                                                          \
        float g0a = __builtin_bit_cast(float, (w0) << 16);                     \
        float g1a = __builtin_bit_cast(float, (w1) << 16);                     \
        float g0b = __builtin_bit_cast(float, (w0) & 0xFFFF0000u);             \
        float g1b = __builtin_bit_cast(float, (w1) & 0xFFFF0000u);             \
        pk[2*(j)]   = bf16r(fmaf(f, g1a - g0a, g0a));                          \
        pk[2*(j)+1] = bf16r(fmaf(f, g1b - g0b, g0b));                          \
    }

#define GST(kk, CHECKED)                                                       \
    {                                                                          \
        const int k = (kk) >> 1;                                               \
        const int m = (((kk) & 1) << 2) + s;         /* chunk 0..7 */          \
        const float f = frr[k];                                                \
        ushort8 pk;                                                            \
        if (!(CHECKED) || (unsigned)r0r[k] <= (unsigned)(XROWS - 2)) {         \
            const int r0 = r0r[k], r1 = r0r[k] + 1;                            \
            uint4 u0 = *(const uint4*)((const char*)xt + r0 * 128 + ((m * 16) ^ ((r0 & 7) << 4))); \
            uint4 u1 = *(const uint4*)((const char*)xt + r1 * 128 + ((m * 16) ^ ((r1 & 7) << 4))); \
            LERPP(pk, 0, u0.x, u1.x, f) LERPP(pk, 1, u0.y, u1.y, f)            \
            LERPP(pk, 2, u0.z, u1.z, f) LERPP(pk, 3, u0.w, u1.w, f)            \
        } else {                                                               \
            int j0 = reflmap(i0r[k]), j1 = reflmap(i0r[k] + 1);                \
            const float* xc = xb0 + (size_t)(m << 3) * LEN;                    \
            _Pragma("unroll")                                                  \
            for (int e = 0; e < 8; ++e) {                                      \
                float g0 = xc[j0], g1 = xc[j1];                                \
                pk[e] = bf16r(fmaf(f, g1 - g0, g0));                           \
                xc += LEN;                                                     \
            }                                                                  \
        }                                                                      \
        short8 bv = __builtin_bit_cast(short8, pk);                            \
        short8 a0 = *(const short8*)&wfl[(0 * 10 + (kk)) * 512];               \
        short8 a1 = *(const short8*)&wfl[(1 * 10 + (kk)) * 512];               \
        short8 a2 = *(const short8*)&wfl[(2 * 10 + (kk)) * 512];               \
        short8 a3 = *(const short8*)&wfl[(3 * 10 + (kk)) * 512];               \
        acc0 = __builtin_amdgcn_mfma_f32_16x16x32_bf16(a0, bv, acc0, 0, 0, 0); \
        acc1 = __builtin_amdgcn_mfma_f32_16x16x32_bf16(a1, bv, acc1, 0, 0, 0); \
        acc2 = __builtin_amdgcn_mfma_f32_16x16x32_bf16(a2, bv, acc2, 0, 0, 0); \
        acc3 = __builtin_amdgcn_mfma_f32_16x16x32_bf16(a3, bv, acc3, 0, 0, 0); \
    }

    #pragma unroll
    for (int it = 0; it < 2; ++it) {
        const int tc = T0 + it * 64 + w * 16 + pl;
        int i0r[KS]; float frr[KS]; int r0r[KS]; bool fastg = true;
        #pragma unroll
        for (int k = 0; k < KS; ++k) {
            float T = (float)(tc + k) + of[it][k];
            T = fminf(fmaxf(T, 0.0f), (float)(LP - 1));
            int i0 = (int)floorf(T);
            i0 = min(i0, LP - 2); i0 = max(i0, 0);
            i0r[k] = i0; frr[k] = T - (float)i0; r0r[k] = i0 - S0;
            fastg = fastg && ((unsigned)(i0 - S0) <= (unsigned)(XROWS - 2));
        }
        f32x4 acc0 = {}, acc1 = {}, acc2 = {}, acc3 = {};
        if (fastg) { GST(0,0) GST(1,0) GST(2,0) GST(3,0) GST(4,0)
                     GST(5,0) GST(6,0) GST(7,0) GST(8,0) GST(9,0) }
        else       { GST(0,1) GST(1,1) GST(2,1) GST(3,1) GST(4,1)
                     GST(5,1) GST(6,1) GST(7,1) GST(8,1) GST(9,1) }
        #pragma unroll
        for (int ot = 0; ot < 4; ++ot) {
            const f32x4 a = (ot==0)?acc0:(ot==1)?acc1:(ot==2)?acc2:acc3;
            #pragma unroll
            for (int r = 0; r < 4; ++r) {
                int o = ot * 16 + s * 4 + r;
                out[((size_t)(b * COUT + o)) * LEN + tc] = a[r] + bias[o];
            }
        }
    }
#undef GST
#undef LERPP
}

extern "C" void kernel_launch(void* const* d_in, const int* in_sizes, int n_in,
                              void* d_out, int out_size, void* d_ws, size_t ws_size,
                              hipStream_t stream) {
    const float* x    = (const float*)d_in[0];
    const float* offs = (const float*)d_in[1];
    const float* w    = (const float*)d_in[2];
    const float* bias = (const float*)d_in[3];
    float* out = (float*)d_out;
    unsigned short* wf = (unsigned short*)d_ws;   // 40960 B

    wfrag_kernel<<<80, 256, 0, stream>>>(w, wf);
    deform_mfma_kernel<<<BATCH * (LEN / TTB), 256, 0, stream>>>(x, offs, wf, bias, out);
}

// Round 17
// 44.678 us; speedup vs baseline: 1.1232x; 1.1232x over previous
//
#include <hip/hip_runtime.h>

#define BATCH 8
#define CIN   64
#define COUT  64
#define LEN   16384
#define KS    5
#define PADW  2
#define LP    (LEN + 2*PADW)
#define TTB   128            // cols per block (2 subtiles of 64)
#define XROWS 104            // staged rows per subtile window
#define XM    14             // S0 = t0s - 14 => x idx of row r = t0s - 16 + r (16B aligned)

typedef __attribute__((ext_vector_type(8)))  short short8;
typedef __attribute__((ext_vector_type(4)))  float f32x4;
typedef __attribute__((ext_vector_type(8)))  unsigned short ushort8;

__device__ __forceinline__ unsigned short bf16r(float f) {
    unsigned u = __builtin_bit_cast(unsigned, f);
    u += 0x7FFF + ((u >> 16) & 1);          // RNE
    return (unsigned short)(u >> 16);
}
__device__ __forceinline__ int reflmap(int s) {  // padded idx -> x idx
    return (s < PADW) ? (PADW - s) : ((s < LEN + PADW) ? (s - PADW) : (2*LEN - s));
}

// W (f32 [o][c][k]) -> bf16 A-frags for mfma_f32_16x16x32_bf16, K k-major
// (ck' = ktap*64 + c).  wf[((ot*10 + kk)*64 + lane)*8 + e]
__global__ void wfrag_kernel(const float* __restrict__ w, unsigned short* __restrict__ wf) {
    int el = blockIdx.x * 256 + threadIdx.x;          // 20480 total
    int e    = el & 7;
    int lane = (el >> 3) & 63;
    int kk   = (el >> 9) % 10;
    int ot   = el / 5120;
    int o    = ot * 16 + (lane & 15);
    int kg   = kk * 32 + ((lane >> 4) << 3) + e;      // ck' 0..319
    int ktap = kg >> 6;
    int c    = kg & 63;
    wf[el] = bf16r(w[(o * 64 + c) * 5 + ktap]);
}

__global__ __launch_bounds__(256, 4) void deform_mfma_kernel(
    const float* __restrict__ x, const float* __restrict__ offs,
    const unsigned short* __restrict__ wf, const float* __restrict__ bias,
    float* __restrict__ out)
{
    __shared__ __align__(16) unsigned short xtl[2][XROWS * 64];   // 2 x 13312 B

    const int tid = threadIdx.x;
    const int bt  = blockIdx.x;              // NO xcd swizzle (L2 thrash, r16)
    const int b   = bt >> 7;
    const int T0  = (bt & 127) * TTB;
    const int w   = tid >> 6;
    const int lane = tid & 63;
    const int pl  = lane & 15;
    const int s   = lane >> 4;

    const float* xb0 = x + (size_t)b * CIN * LEN;
    const unsigned short* wfl = wf + (size_t)lane * 8;

    // ---- preload offsets for both subtiles ----
    float of[2][KS];
    #pragma unroll
    for (int it = 0; it < 2; ++it) {
        const int tc = T0 + it * 64 + w * 16 + pl;
        #pragma unroll
        for (int k = 0; k < KS; ++k)
            of[it][k] = offs[((size_t)(b * LEN + tc)) * KS + k];
    }

    float4 sA[4], sB[4];
    int stg_fast;

    // row r of subtile window = xp[S0+r] = x[t0s-16+r]; base 16B aligned
#define STAGE_LOAD(t0s)                                                        \
    stg_fast = ((t0s) >= 16 && (t0s) + 88 <= LEN);                             \
    if (stg_fast) {                                                            \
        const float* src0 = xb0 + ((t0s) - 16);                                \
        _Pragma("unroll")                                                      \
        for (int rep = 0; rep < 4; ++rep) {                                    \
            int task = rep * 256 + tid;          /* 832 = 64 ch x 13 strips */ \
            if (task < 832) {                                                  \
                int c = task / 13, q = task - c * 13;                          \
                const float* p = src0 + (size_t)c * LEN + 8 * q;               \
                sA[rep] = *(const float4*)p;                                   \
                sB[rep] = *(const float4*)(p + 4);                             \
            }                                                                  \
        }                                                                      \
    }

#define STAGE_WRITE(dst, t0s)                                                  \
    if (stg_fast) {                                                            \
        _Pragma("unroll")                                                      \
        for (int rep = 0; rep < 4; ++rep) {                                    \
            int task = rep * 256 + tid;                                        \
            if (task < 832) {                                                  \
                int c = task / 13, q = task - c * 13;                          \
                float vv[8] = {sA[rep].x, sA[rep].y, sA[rep].z, sA[rep].w,     \
                               sB[rep].x, sB[rep].y, sB[rep].z, sB[rep].w};    \
                _Pragma("unroll")                                              \
                for (int i = 0; i < 8; ++i) {                                  \
                    int r = 8 * q + i;                                         \
                    *(unsigned short*)((char*)(dst) + r * 128 +                \
                        ((2 * c) ^ ((r & 7) << 4))) = bf16r(vv[i]);            \
                }                                                              \
            }                                                                  \
        }                                                                      \
    } else {                                                                   \
        const int S0e = (t0s) - XM;                                            \
        _Pragma("unroll")                                                      \
        for (int rep = 0; rep < 26; ++rep) {                                   \
            int idx = rep * 256 + tid;           /* 6656 = 104 x 64 */         \
            int r = idx >> 6, c = idx & 63;                                    \
            int sp = min(max(S0e + r, 0), LP - 1);                             \
            *(unsigned short*)((char*)(dst) + r * 128 +                        \
                ((2 * c) ^ ((r & 7) << 4))) = bf16r(xb0[(size_t)c * LEN + reflmap(sp)]); \
        }                                                                      \
    }

#define LERPP(pk, j, w0, w1, f)                                                \
    {                                                                          \
        float g0a = __builtin_bit_cast(float, (w0) << 16);                     \
        float g1a = __builtin_bit_cast(float, (w1) << 16);                     \
        float g0b = __builtin_bit_cast(float, (w0) & 0xFFFF0000u);             \
        float g1b = __builtin_bit_cast(float, (w1) & 0xFFFF0000u);             \
        pk[2*(j)]   = bf16r(fmaf(f, g1a - g0a, g0a));                          \
        pk[2*(j)+1] = bf16r(fmaf(f, g1b - g0b, g0b));                          \
    }

    // pipelined fast-path gather: GLOAD issues 2 ds_read_b128, GCOMP converts+MFMAs
#define GLOAD(kk)                                                              \
    {                                                                          \
        const int r0 = r0r[(kk) >> 1], r1 = r0 + 1;                            \
        const int mm = ((((kk) & 1) << 2) + s) * 16;                           \
        U0[kk] = *(const uint4*)((const char*)xbuf + r0 * 128 + (mm ^ ((r0 & 7) << 4))); \
        U1[kk] = *(const uint4*)((const char*)xbuf + r1 * 128 + (mm ^ ((r1 & 7) << 4))); \
    }

#define GCOMP(kk)                                                              \
    {                                                                          \
        const float f = frr[(kk) >> 1];                                        \
        ushort8 pk;                                                            \
        LERPP(pk, 0, U0[kk].x, U1[kk].x, f) LERPP(pk, 1, U0[kk].y, U1[kk].y, f)\
        LERPP(pk, 2, U0[kk].z, U1[kk].z, f) LERPP(pk, 3, U0[kk].w, U1[kk].w, f)\
        short8 bv = __builtin_bit_cast(short8, pk);                            \
        short8 a0 = *(const short8*)&wfl[(0 * 10 + (kk)) * 512];               \
        short8 a1 = *(const short8*)&wfl[(1 * 10 + (kk)) * 512];               \
        short8 a2 = *(const short8*)&wfl[(2 * 10 + (kk)) * 512];               \
        short8 a3 = *(const short8*)&wfl[(3 * 10 + (kk)) * 512];               \
        acc0 = __builtin_amdgcn_mfma_f32_16x16x32_bf16(a0, bv, acc0, 0, 0, 0); \
        acc1 = __builtin_amdgcn_mfma_f32_16x16x32_bf16(a1, bv, acc1, 0, 0, 0); \
        acc2 = __builtin_amdgcn_mfma_f32_16x16x32_bf16(a2, bv, acc2, 0, 0, 0); \
        acc3 = __builtin_amdgcn_mfma_f32_16x16x32_bf16(a3, bv, acc3, 0, 0, 0); \
    }

#define GSLOW(kk)                                                              \
    {                                                                          \
        const int k = (kk) >> 1;                                               \
        const int m = (((kk) & 1) << 2) + s;                                   \
        const float f = frr[k];                                                \
        ushort8 pk;                                                            \
        int j0 = reflmap(i0r[k]), j1 = reflmap(i0r[k] + 1);                    \
        const float* xc = xb0 + (size_t)(m << 3) * LEN;                        \
        _Pragma("unroll")                                                      \
        for (int e = 0; e < 8; ++e) {                                          \
            float g0 = xc[j0], g1 = xc[j1];                                    \
            pk[e] = bf16r(fmaf(f, g1 - g0, g0));                               \
            xc += LEN;                                                         \
        }                                                                      \
        short8 bv = __builtin_bit_cast(short8, pk);                            \
        short8 a0 = *(const short8*)&wfl[(0 * 10 + (kk)) * 512];               \
        short8 a1 = *(const short8*)&wfl[(1 * 10 + (kk)) * 512];               \
        short8 a2 = *(const short8*)&wfl[(2 * 10 + (kk)) * 512];               \
        short8 a3 = *(const short8*)&wfl[(3 * 10 + (kk)) * 512];               \
        acc0 = __builtin_amdgcn_mfma_f32_16x16x32_bf16(a0, bv, acc0, 0, 0, 0); \
        acc1 = __builtin_amdgcn_mfma_f32_16x16x32_bf16(a1, bv, acc1, 0, 0, 0); \
        acc2 = __builtin_amdgcn_mfma_f32_16x16x32_bf16(a2, bv, acc2, 0, 0, 0); \
        acc3 = __builtin_amdgcn_mfma_f32_16x16x32_bf16(a3, bv, acc3, 0, 0, 0); \
    }

#define SUBTILE(it)                                                            \
    {                                                                          \
        const int t0s = T0 + (it) * 64;                                        \
        if ((it) == 0) { STAGE_LOAD(t0s + 64); }   /* issue next-tile loads */ \
        const int S0 = t0s - XM;                                               \
        const int tc = t0s + w * 16 + pl;                                      \
        int i0r[KS]; float frr[KS]; int r0r[KS]; bool fastg = true;            \
        _Pragma("unroll")                                                      \
        for (int k = 0; k < KS; ++k) {                                         \
            float T = (float)(tc + k) + of[it][k];                             \
            T = fminf(fmaxf(T, 0.0f), (float)(LP - 1));                        \
            int i0 = (int)floorf(T);                                           \
            i0 = min(i0, LP - 2); i0 = max(i0, 0);                             \
            i0r[k] = i0; frr[k] = T - (float)i0; r0r[k] = i0 - S0;             \
            fastg = fastg && ((unsigned)(i0 - S0) <= (unsigned)(XROWS - 2));   \
        }                                                                      \
        const unsigned short* xbuf = xtl[(it)];                                \
        f32x4 acc0 = {}, acc1 = {}, acc2 = {}, acc3 = {};                      \
        if (fastg) {                                                           \
            uint4 U0[10], U1[10];                                              \
            GLOAD(0) GLOAD(1) GLOAD(2) GLOAD(3) GLOAD(4)                       \
            GCOMP(0) GLOAD(5) GCOMP(1) GLOAD(6) GCOMP(2) GLOAD(7)              \
            GCOMP(3) GLOAD(8) GCOMP(4) GLOAD(9)                                \
            GCOMP(5) GCOMP(6) GCOMP(7) GCOMP(8) GCOMP(9)                       \
        } else {                                                               \
            GSLOW(0) GSLOW(1) GSLOW(2) GSLOW(3) GSLOW(4)                       \
            GSLOW(5) GSLOW(6) GSLOW(7) GSLOW(8) GSLOW(9)                       \
        }                                                                      \
        _Pragma("unroll")                                                      \
        for (int ot = 0; ot < 4; ++ot) {                                       \
            const f32x4 a = (ot==0)?acc0:(ot==1)?acc1:(ot==2)?acc2:acc3;       \
            _Pragma("unroll")                                                  \
            for (int r = 0; r < 4; ++r) {                                      \
                int o = ot * 16 + s * 4 + r;                                   \
                out[((size_t)(b * COUT + o)) * LEN + tc] = a[r] + bias[o];     \
            }                                                                  \
        }                                                                      \
        if ((it) == 0) { STAGE_WRITE(xtl[1], t0s + 64); __syncthreads(); }     \
    }

    // ---- prologue: stage subtile 0 ----
    STAGE_LOAD(T0);
    STAGE_WRITE(xtl[0], T0);
    __syncthreads();

    SUBTILE(0)
    SUBTILE(1)

#undef SUBTILE
#undef GSLOW
#undef GCOMP
#undef GLOAD
#undef LERPP
#undef STAGE_WRITE
#undef STAGE_LOAD
}

extern "C" void kernel_launch(void* const* d_in, const int* in_sizes, int n_in,
                              void* d_out, int out_size, void* d_ws, size_t ws_size,
                              hipStream_t stream) {
    const float* x    = (const float*)d_in[0];
    const float* offs = (const float*)d_in[1];
    const float* w    = (const float*)d_in[2];
    const float* bias = (const float*)d_in[3];
    float* out = (float*)d_out;
    unsigned short* wf = (unsigned short*)d_ws;   // 40960 B

    wfrag_kernel<<<80, 256, 0, stream>>>(w, wf);
    deform_mfma_kernel<<<BATCH * (LEN / TTB), 256, 0, stream>>>(x, offs, wf, bias, out);
}

// Round 18
// 34.535 us; speedup vs baseline: 1.4530x; 1.2937x over previous
//
#include <hip/hip_runtime.h>

#define BATCH 8
#define CIN   64
#define COUT  64
#define LEN   16384
#define KS    5
#define PADW  2
#define LP    (LEN + 2*PADW)
#define TTB   128            // cols per block (2 subtiles of 64)
#define XROWS 104            // staged rows per subtile window
#define XM    14             // S0 = t0s - 14 => x idx of row r = t0s - 16 + r (16B aligned)

typedef __attribute__((ext_vector_type(8)))  short short8;
typedef __attribute__((ext_vector_type(4)))  float f32x4;
typedef __attribute__((ext_vector_type(8)))  unsigned short ushort8;

__device__ __forceinline__ unsigned short bf16r(float f) {
    unsigned u = __builtin_bit_cast(unsigned, f);
    u += 0x7FFF + ((u >> 16) & 1);          // RNE
    return (unsigned short)(u >> 16);
}
// fast pack: round-half-up both floats to bf16, pack into one u32 (1 v_perm)
__device__ __forceinline__ unsigned fpack(float a, float b) {
    unsigned ua = __builtin_bit_cast(unsigned, a) + 0x8000u;
    unsigned ub = __builtin_bit_cast(unsigned, b) + 0x8000u;
    return __builtin_amdgcn_perm(ub, ua, 0x07060302);   // [ub.b3 ub.b2 ua.b3 ua.b2]
}
__device__ __forceinline__ int reflmap(int s) {  // padded idx -> x idx
    return (s < PADW) ? (PADW - s) : ((s < LEN + PADW) ? (s - PADW) : (2*LEN - s));
}

// W (f32 [o][c][k]) -> bf16 A-frags for mfma_f32_16x16x32_bf16, K k-major
// (ck' = ktap*64 + c).  wf[((ot*10 + kk)*64 + lane)*8 + e]
__global__ void wfrag_kernel(const float* __restrict__ w, unsigned short* __restrict__ wf) {
    int el = blockIdx.x * 256 + threadIdx.x;          // 20480 total
    int e    = el & 7;
    int lane = (el >> 3) & 63;
    int kk   = (el >> 9) % 10;
    int ot   = el / 5120;
    int o    = ot * 16 + (lane & 15);
    int kg   = kk * 32 + ((lane >> 4) << 3) + e;      // ck' 0..319
    int ktap = kg >> 6;
    int c    = kg & 63;
    wf[el] = bf16r(w[(o * 64 + c) * 5 + ktap]);
}

__global__ __launch_bounds__(256, 4) void deform_mfma_kernel(
    const float* __restrict__ x, const float* __restrict__ offs,
    const unsigned short* __restrict__ wf, const float* __restrict__ bias,
    float* __restrict__ out)
{
    __shared__ __align__(16) unsigned short xtl[2][XROWS * 64];   // 2 x 13312 B

    const int tid = threadIdx.x;
    const int bid = blockIdx.x;
    const int bt  = (bid & 7) * 128 + (bid >> 3);    // XCD swizzle (r14-proven)
    const int b   = bt >> 7;
    const int T0  = (bt & 127) * TTB;
    const int w   = tid >> 6;
    const int lane = tid & 63;
    const int pl  = lane & 15;
    const int s   = lane >> 4;

    const float* xb0 = x + (size_t)b * CIN * LEN;
    const unsigned short* wfl = wf + (size_t)lane * 8;

    // ---- preload offsets for both subtiles ----
    float of[2][KS];
    #pragma unroll
    for (int it = 0; it < 2; ++it) {
        const int tc = T0 + it * 64 + w * 16 + pl;
        #pragma unroll
        for (int k = 0; k < KS; ++k)
            of[it][k] = offs[((size_t)(b * LEN + tc)) * KS + k];
    }

    float4 vA0[2], vA1[2], vB0[2], vB1[2];
    int stg_fast;

    // row r of subtile window = xp[S0+r] = x[t0s-16+r]; base 16B aligned.
    // fast staging: 416 tasks = 32 ch-pairs x 13 row-strips(8)
#define STAGE_LOAD(t0s)                                                        \
    stg_fast = ((t0s) >= 16 && (t0s) + 88 <= LEN);                             \
    if (stg_fast) {                                                            \
        const float* src0 = xb0 + ((t0s) - 16);                                \
        _Pragma("unroll")                                                      \
        for (int rep = 0; rep < 2; ++rep) {                                    \
            int task = rep * 256 + tid;                                        \
            if (task < 416) {                                                  \
                int c2 = task / 13, q = task - c2 * 13;                        \
                const float* p0 = src0 + (size_t)(2 * c2) * LEN + 8 * q;       \
                vA0[rep] = *(const float4*)p0;                                 \
                vA1[rep] = *(const float4*)(p0 + 4);                           \
                vB0[rep] = *(const float4*)(p0 + LEN);                         \
                vB1[rep] = *(const float4*)(p0 + LEN + 4);                     \
            }                                                                  \
        }                                                                      \
    }

#define STAGE_WRITE(dst, t0s)                                                  \
    if (stg_fast) {                                                            \
        _Pragma("unroll")                                                      \
        for (int rep = 0; rep < 2; ++rep) {                                    \
            int task = rep * 256 + tid;                                        \
            if (task < 416) {                                                  \
                int c2 = task / 13, q = task - c2 * 13;                        \
                float av[8] = {vA0[rep].x, vA0[rep].y, vA0[rep].z, vA0[rep].w, \
                               vA1[rep].x, vA1[rep].y, vA1[rep].z, vA1[rep].w};\
                float bv[8] = {vB0[rep].x, vB0[rep].y, vB0[rep].z, vB0[rep].w, \
                               vB1[rep].x, vB1[rep].y, vB1[rep].z, vB1[rep].w};\
                _Pragma("unroll")                                              \
                for (int i = 0; i < 8; ++i) {                                  \
                    int r = 8 * q + i;                                         \
                    *(unsigned*)((char*)(dst) + r * 128 +                      \
                        ((4 * c2) ^ ((r & 7) << 4))) = fpack(av[i], bv[i]);    \
                }                                                              \
            }                                                                  \
        }                                                                      \
    } else {                                                                   \
        const int S0e = (t0s) - XM;                                            \
        _Pragma("unroll")                                                      \
        for (int rep = 0; rep < 26; ++rep) {                                   \
            int idx = rep * 256 + tid;           /* 6656 = 104 x 64 */         \
            int r = idx >> 6, c = idx & 63;                                    \
            int sp = min(max(S0e + r, 0), LP - 1);                             \
            *(unsigned short*)((char*)(dst) + r * 128 +                        \
                ((2 * c) ^ ((r & 7) << 4))) = bf16r(xb0[(size_t)c * LEN + reflmap(sp)]); \
        }                                                                      \
    }

    // lerp 2 channels from pair-words (w0=row i0, w1=row i0+1), fast pack
#define LERPW(dst, w0, w1, f)                                                  \
    {                                                                          \
        float g0a = __builtin_bit_cast(float, (w0) << 16);                     \
        float g1a = __builtin_bit_cast(float, (w1) << 16);                     \
        float g0b = __builtin_bit_cast(float, (w0) & 0xFFFF0000u);             \
        float g1b = __builtin_bit_cast(float, (w1) & 0xFFFF0000u);             \
        dst = fpack(fmaf(f, g1a - g0a, g0a), fmaf(f, g1b - g0b, g0b));         \
    }

#define GST(kk, CHECKED)                                                       \
    {                                                                          \
        const int k = (kk) >> 1;                                               \
        const int m = (((kk) & 1) << 2) + s;         /* chunk 0..7 */          \
        const float f = frr[k];                                                \
        uint4 pw;                                                              \
        if (!(CHECKED) || (unsigned)r0r[k] <= (unsigned)(XROWS - 2)) {         \
            const int r0 = r0r[k], r1 = r0r[k] + 1;                            \
            uint4 u0 = *(const uint4*)((const char*)xbuf + r0 * 128 + ((m * 16) ^ ((r0 & 7) << 4))); \
            uint4 u1 = *(const uint4*)((const char*)xbuf + r1 * 128 + ((m * 16) ^ ((r1 & 7) << 4))); \
            LERPW(pw.x, u0.x, u1.x, f) LERPW(pw.y, u0.y, u1.y, f)              \
            LERPW(pw.z, u0.z, u1.z, f) LERPW(pw.w, u0.w, u1.w, f)              \
        } else {                                                               \
            int j0 = reflmap(i0r[k]), j1 = reflmap(i0r[k] + 1);                \
            const float* xc = xb0 + (size_t)(m << 3) * LEN;                    \
            unsigned pv[4];                                                    \
            _Pragma("unroll")                                                  \
            for (int e = 0; e < 4; ++e) {                                      \
                float ga0 = xc[j0], ga1 = xc[j1];                              \
                float lo = fmaf(f, ga1 - ga0, ga0);                            \
                float gb0 = xc[LEN + j0], gb1 = xc[LEN + j1];                  \
                float hi = fmaf(f, gb1 - gb0, gb0);                            \
                pv[e] = fpack(lo, hi);                                         \
                xc += 2 * LEN;                                                 \
            }                                                                  \
            pw = uint4{pv[0], pv[1], pv[2], pv[3]};                            \
        }                                                                      \
        short8 bv = __builtin_bit_cast(short8, pw);                            \
        short8 a0 = *(const short8*)&wfl[(0 * 10 + (kk)) * 512];               \
        short8 a1 = *(const short8*)&wfl[(1 * 10 + (kk)) * 512];               \
        short8 a2 = *(const short8*)&wfl[(2 * 10 + (kk)) * 512];               \
        short8 a3 = *(const short8*)&wfl[(3 * 10 + (kk)) * 512];               \
        acc0 = __builtin_amdgcn_mfma_f32_16x16x32_bf16(a0, bv, acc0, 0, 0, 0); \
        acc1 = __builtin_amdgcn_mfma_f32_16x16x32_bf16(a1, bv, acc1, 0, 0, 0); \
        acc2 = __builtin_amdgcn_mfma_f32_16x16x32_bf16(a2, bv, acc2, 0, 0, 0); \
        acc3 = __builtin_amdgcn_mfma_f32_16x16x32_bf16(a3, bv, acc3, 0, 0, 0); \
    }

#define SUBTILE(it)                                                            \
    {                                                                          \
        const int t0s = T0 + (it) * 64;                                        \
        if ((it) == 0) { STAGE_LOAD(t0s + 64); }   /* issue next-tile loads */ \
        const int S0 = t0s - XM;                                               \
        const int tc = t0s + w * 16 + pl;                                      \
        int i0r[KS]; float frr[KS]; int r0r[KS]; bool fastg = true;            \
        _Pragma("unroll")                                                      \
        for (int k = 0; k < KS; ++k) {                                         \
            float T = (float)(tc + k) + of[it][k];                             \
            T = fminf(fmaxf(T, 0.0f), (float)(LP - 1));                        \
            int i0 = (int)floorf(T);                                           \
            i0 = min(i0, LP - 2); i0 = max(i0, 0);                             \
            i0r[k] = i0; frr[k] = T - (float)i0; r0r[k] = i0 - S0;             \
            fastg = fastg && ((unsigned)(i0 - S0) <= (unsigned)(XROWS - 2));   \
        }                                                                      \
        const unsigned short* xbuf = xtl[(it)];                                \
        f32x4 acc0 = {}, acc1 = {}, acc2 = {}, acc3 = {};                      \
        if (fastg) { GST(0,0) GST(1,0) GST(2,0) GST(3,0) GST(4,0)              \
                     GST(5,0) GST(6,0) GST(7,0) GST(8,0) GST(9,0) }            \
        else       { GST(0,1) GST(1,1) GST(2,1) GST(3,1) GST(4,1)              \
                     GST(5,1) GST(6,1) GST(7,1) GST(8,1) GST(9,1) }            \
        _Pragma("unroll")                                                      \
        for (int ot = 0; ot < 4; ++ot) {                                       \
            const f32x4 a = (ot==0)?acc0:(ot==1)?acc1:(ot==2)?acc2:acc3;       \
            _Pragma("unroll")                                                  \
            for (int r = 0; r < 4; ++r) {                                      \
                int o = ot * 16 + s * 4 + r;                                   \
                out[((size_t)(b * COUT + o)) * LEN + tc] = a[r] + bias[o];     \
            }                                                                  \
        }                                                                      \
        if ((it) == 0) { STAGE_WRITE(xtl[1], t0s + 64); __syncthreads(); }     \
    }

    // ---- prologue: stage subtile 0 ----
    STAGE_LOAD(T0);
    STAGE_WRITE(xtl[0], T0);
    __syncthreads();

    SUBTILE(0)
    SUBTILE(1)

#undef SUBTILE
#undef GST
#undef LERPW
#undef STAGE_WRITE
#undef STAGE_LOAD
}

extern "C" void kernel_launch(void* const* d_in, const int* in_sizes, int n_in,
                              void* d_out, int out_size, void* d_ws, size_t ws_size,
                              hipStream_t stream) {
    const float* x    = (const float*)d_in[0];
    const float* offs = (const float*)d_in[1];
    const float* w    = (const float*)d_in[2];
    const float* bias = (const float*)d_in[3];
    float* out = (float*)d_out;
    unsigned short* wf = (unsigned short*)d_ws;   // 40960 B

    wfrag_kernel<<<80, 256, 0, stream>>>(w, wf);
    deform_mfma_kernel<<<BATCH * (LEN / TTB), 256, 0, stream>>>(x, offs, wf, bias, out);
}

// Round 19
// 31.827 us; speedup vs baseline: 1.5767x; 1.0851x over previous
//
#include <hip/hip_runtime.h>

#define BATCH 8
#define CIN   64
#define COUT  64
#define LEN   16384
#define KS    5
#define PADW  2
#define LP    (LEN + 2*PADW)
#define TTB   128            // cols per block (2 subtiles of 64, fused compute)
#define XROWS 104            // staged rows per subtile window
#define XM    14             // S0 = t0s - 14 => x idx of row r = t0s - 16 + r (16B aligned)

typedef __attribute__((ext_vector_type(8)))  short short8;
typedef __attribute__((ext_vector_type(4)))  float f32x4;

__device__ __forceinline__ unsigned short bf16r(float f) {
    unsigned u = __builtin_bit_cast(unsigned, f);
    u += 0x7FFF + ((u >> 16) & 1);          // RNE
    return (unsigned short)(u >> 16);
}
// fast pack: round-half-up both floats to bf16, pack into one u32 (1 v_perm)
__device__ __forceinline__ unsigned fpack(float a, float b) {
    unsigned ua = __builtin_bit_cast(unsigned, a) + 0x8000u;
    unsigned ub = __builtin_bit_cast(unsigned, b) + 0x8000u;
    return __builtin_amdgcn_perm(ub, ua, 0x07060302);   // [ub.b3 ub.b2 ua.b3 ua.b2]
}
__device__ __forceinline__ int reflmap(int s) {  // padded idx -> x idx
    return (s < PADW) ? (PADW - s) : ((s < LEN + PADW) ? (s - PADW) : (2*LEN - s));
}

// W (f32 [o][c][k]) -> bf16 A-frags for mfma_f32_16x16x32_bf16, K k-major
// (ck' = ktap*64 + c).  wf[((ot*10 + kk)*64 + lane)*8 + e]
__global__ void wfrag_kernel(const float* __restrict__ w, unsigned short* __restrict__ wf) {
    int el = blockIdx.x * 256 + threadIdx.x;          // 20480 total
    int e    = el & 7;
    int lane = (el >> 3) & 63;
    int kk   = (el >> 9) % 10;
    int ot   = el / 5120;
    int o    = ot * 16 + (lane & 15);
    int kg   = kk * 32 + ((lane >> 4) << 3) + e;      // ck' 0..319
    int ktap = kg >> 6;
    int c    = kg & 63;
    wf[el] = bf16r(w[(o * 64 + c) * 5 + ktap]);
}

__global__ __launch_bounds__(256, 4) void deform_mfma_kernel(
    const float* __restrict__ x, const float* __restrict__ offs,
    const unsigned short* __restrict__ wf, const float* __restrict__ bias,
    float* __restrict__ out)
{
    __shared__ __align__(16) unsigned short xtl[2][XROWS * 64];   // 2 x 13312 B

    const int tid = threadIdx.x;
    const int bid = blockIdx.x;
    const int bt  = (bid & 7) * 128 + (bid >> 3);    // XCD swizzle (r14-proven)
    const int b   = bt >> 7;
    const int T0  = (bt & 127) * TTB;
    const int w   = tid >> 6;
    const int lane = tid & 63;
    const int pl  = lane & 15;
    const int s   = lane >> 4;

    const float* xb0 = x + (size_t)b * CIN * LEN;
    const unsigned short* wfl = wf + (size_t)lane * 8;

    // ---- preload offsets for both subtiles ----
    float of0[KS], of1[KS];
    {
        const int tcா = T0 + w * 16 + pl;
        #pragma unroll
        for (int k = 0; k < KS; ++k) of0[k] = offs[((size_t)(b * LEN + tcா)) * KS + k];
        #pragma unroll
        for (int k = 0; k < KS; ++k) of1[k] = offs[((size_t)(b * LEN + tcா + 64)) * KS + k];
    }

    float4 vA0[2], vA1[2], vB0[2], vB1[2];
    int stg_fast;

    // row r of subtile window = xp[S0+r] = x[t0s-16+r]; base 16B aligned.
#define STAGE_LOAD(t0s)                                                        \
    stg_fast = ((t0s) >= 16 && (t0s) + 88 <= LEN);                             \
    if (stg_fast) {                                                            \
        const float* src0 = xb0 + ((t0s) - 16);                                \
        _Pragma("unroll")                                                      \
        for (int rep = 0; rep < 2; ++rep) {                                    \
            int task = rep * 256 + tid;          /* 416 = 32 ch-pairs x 13 */  \
            if (task < 416) {                                                  \
                int c2 = task / 13, q = task - c2 * 13;                        \
                const float* p0 = src0 + (size_t)(2 * c2) * LEN + 8 * q;       \
                vA0[rep] = *(const float4*)p0;                                 \
                vA1[rep] = *(const float4*)(p0 + 4);                           \
                vB0[rep] = *(const float4*)(p0 + LEN);                         \
                vB1[rep] = *(const float4*)(p0 + LEN + 4);                     \
            }                                                                  \
        }                                                                      \
    }

#define STAGE_WRITE(dst, t0s)                                                  \
    if (stg_fast) {                                                            \
        _Pragma("unroll")                                                      \
        for (int rep = 0; rep < 2; ++rep) {                                    \
            int task = rep * 256 + tid;                                        \
            if (task < 416) {                                                  \
                int c2 = task / 13, q = task - c2 * 13;                        \
                float av[8] = {vA0[rep].x, vA0[rep].y, vA0[rep].z, vA0[rep].w, \
                               vA1[rep].x, vA1[rep].y, vA1[rep].z, vA1[rep].w};\
                float bv[8] = {vB0[rep].x, vB0[rep].y, vB0[rep].z, vB0[rep].w, \
                               vB1[rep].x, vB1[rep].y, vB1[rep].z, vB1[rep].w};\
                _Pragma("unroll")                                              \
                for (int i = 0; i < 8; ++i) {                                  \
                    int r = 8 * q + i;                                         \
                    *(unsigned*)((char*)(dst) + r * 128 +                      \
                        ((4 * c2) ^ ((r & 7) << 4))) = fpack(av[i], bv[i]);    \
                }                                                              \
            }                                                                  \
        }                                                                      \
    } else {                                                                   \
        const int S0e = (t0s) - XM;                                            \
        _Pragma("unroll")                                                      \
        for (int rep = 0; rep < 26; ++rep) {                                   \
            int idx = rep * 256 + tid;           /* 6656 = 104 x 64 */         \
            int r = idx >> 6, c = idx & 63;                                    \
            int sp = min(max(S0e + r, 0), LP - 1);                             \
            *(unsigned short*)((char*)(dst) + r * 128 +                        \
                ((2 * c) ^ ((r & 7) << 4))) = bf16r(xb0[(size_t)c * LEN + reflmap(sp)]); \
        }                                                                      \
    }

#define LERPW(dst, w0, w1, f)                                                  \
    {                                                                          \
        float g0a = __builtin_bit_cast(float, (w0) << 16);                     \
        float g1a = __builtin_bit_cast(float, (w1) << 16);                     \
        float g0b = __builtin_bit_cast(float, (w0) & 0xFFFF0000u);             \
        float g1b = __builtin_bit_cast(float, (w1) & 0xFFFF0000u);             \
        dst = fpack(fmaf(f, g1a - g0a, g0a), fmaf(f, g1b - g0b, g0b));         \
    }

    // gather one B-frag (fast path) from window XB at row array/frac
#define GATHF(pw, XB, R0A, FRA, k, mm)                                         \
    {                                                                          \
        const int r0 = R0A[k], r1 = r0 + 1;                                    \
        const float f = FRA[k];                                                \
        uint4 u0 = *(const uint4*)((const char*)(XB) + r0 * 128 + ((mm) ^ ((r0 & 7) << 4))); \
        uint4 u1 = *(const uint4*)((const char*)(XB) + r1 * 128 + ((mm) ^ ((r1 & 7) << 4))); \
        LERPW(pw.x, u0.x, u1.x, f) LERPW(pw.y, u0.y, u1.y, f)                  \
        LERPW(pw.z, u0.z, u1.z, f) LERPW(pw.w, u0.w, u1.w, f)                  \
    }

    // gather one B-frag (slow path, exact reflect from global)
#define GATHS(pw, I0A, FRA, k, m)                                              \
    {                                                                          \
        const float f = FRA[k];                                                \
        int j0 = reflmap(I0A[k]), j1 = reflmap(I0A[k] + 1);                    \
        const float* xc = xb0 + (size_t)((m) << 3) * LEN;                      \
        unsigned pv[4];                                                        \
        _Pragma("unroll")                                                      \
        for (int e = 0; e < 4; ++e) {                                          \
            float ga0 = xc[j0], ga1 = xc[j1];                                  \
            float lo = fmaf(f, ga1 - ga0, ga0);                                \
            float gb0 = xc[LEN + j0], gb1 = xc[LEN + j1];                      \
            float hi = fmaf(f, gb1 - gb0, gb0);                                \
            pv[e] = fpack(lo, hi);                                             \
            xc += 2 * LEN;                                                     \
        }                                                                      \
        pw = uint4{pv[0], pv[1], pv[2], pv[3]};                                \
    }

#define MFMA8(kk, pw0, pw1)                                                    \
    {                                                                          \
        short8 bv0 = __builtin_bit_cast(short8, pw0);                          \
        short8 bv1 = __builtin_bit_cast(short8, pw1);                          \
        short8 a0 = *(const short8*)&wfl[(0 * 10 + (kk)) * 512];               \
        short8 a1 = *(const short8*)&wfl[(1 * 10 + (kk)) * 512];               \
        short8 a2 = *(const short8*)&wfl[(2 * 10 + (kk)) * 512];               \
        short8 a3 = *(const short8*)&wfl[(3 * 10 + (kk)) * 512];               \
        accA0 = __builtin_amdgcn_mfma_f32_16x16x32_bf16(a0, bv0, accA0, 0, 0, 0); \
        accB0 = __builtin_amdgcn_mfma_f32_16x16x32_bf16(a0, bv1, accB0, 0, 0, 0); \
        accA1 = __builtin_amdgcn_mfma_f32_16x16x32_bf16(a1, bv0, accA1, 0, 0, 0); \
        accB1 = __builtin_amdgcn_mfma_f32_16x16x32_bf16(a1, bv1, accB1, 0, 0, 0); \
        accA2 = __builtin_amdgcn_mfma_f32_16x16x32_bf16(a2, bv0, accA2, 0, 0, 0); \
        accB2 = __builtin_amdgcn_mfma_f32_16x16x32_bf16(a2, bv1, accB2, 0, 0, 0); \
        accA3 = __builtin_amdgcn_mfma_f32_16x16x32_bf16(a3, bv0, accA3, 0, 0, 0); \
        accB3 = __builtin_amdgcn_mfma_f32_16x16x32_bf16(a3, bv1, accB3, 0, 0, 0); \
    }

#define FUSED(kk)                                                              \
    {                                                                          \
        const int k  = (kk) >> 1;                                              \
        const int mm = ((((kk) & 1) << 2) + s) * 16;                           \
        uint4 pw0, pw1;                                                        \
        GATHF(pw0, xtl[0], r00, fr0, k, mm)                                    \
        GATHF(pw1, xtl[1], r01, fr1, k, mm)                                    \
        MFMA8(kk, pw0, pw1)                                                    \
    }

#define CHECKED1(kk, pw, R0A, I0A, FRA, XB)                                    \
    {                                                                          \
        const int k = (kk) >> 1;                                               \
        const int m = (((kk) & 1) << 2) + s;                                   \
        if ((unsigned)R0A[k] <= (unsigned)(XROWS - 2)) {                       \
            GATHF(pw, XB, R0A, FRA, k, m * 16)                                 \
        } else {                                                               \
            GATHS(pw, I0A, FRA, k, m)                                          \
        }                                                                      \
    }

#define FUSEDC(kk)                                                             \
    {                                                                          \
        uint4 pw0, pw1;                                                        \
        CHECKED1(kk, pw0, r00, i00, fr0, xtl[0])                               \
        CHECKED1(kk, pw1, r01, i01, fr1, xtl[1])                               \
        MFMA8(kk, pw0, pw1)                                                    \
    }

    // ---- stage both windows, then one barrier ----
    STAGE_LOAD(T0);
    STAGE_WRITE(xtl[0], T0);
    STAGE_LOAD(T0 + 64);

    // ---- descriptors for both subtiles (hides under window-1 load latency) ----
    int i00[KS], i01[KS], r00[KS], r01[KS];
    float fr0[KS], fr1[KS];
    bool fastg = true;
    {
        const int tc0 = T0 + w * 16 + pl;
        #pragma unroll
        for (int k = 0; k < KS; ++k) {
            float T = (float)(tc0 + k) + of0[k];
            T = fminf(fmaxf(T, 0.0f), (float)(LP - 1));
            int i0 = (int)floorf(T);
            i0 = min(i0, LP - 2); i0 = max(i0, 0);
            i00[k] = i0; fr0[k] = T - (float)i0; r00[k] = i0 - (T0 - XM);
            fastg = fastg && ((unsigned)r00[k] <= (unsigned)(XROWS - 2));
        }
        #pragma unroll
        for (int k = 0; k < KS; ++k) {
            float T = (float)(tc0 + 64 + k) + of1[k];
            T = fminf(fmaxf(T, 0.0f), (float)(LP - 1));
            int i0 = (int)floorf(T);
            i0 = min(i0, LP - 2); i0 = max(i0, 0);
            i01[k] = i0; fr1[k] = T - (float)i0; r01[k] = i0 - (T0 + 64 - XM);
            fastg = fastg && ((unsigned)r01[k] <= (unsigned)(XROWS - 2));
        }
    }

    STAGE_WRITE(xtl[1], T0 + 64);
    __syncthreads();

    // ---- fused compute: 10 steps x {2 gathers, 4 A-loads, 8 MFMA} ----
    f32x4 accA0 = {}, accA1 = {}, accA2 = {}, accA3 = {};
    f32x4 accB0 = {}, accB1 = {}, accB2 = {}, accB3 = {};
    if (fastg) {
        FUSED(0) FUSED(1) FUSED(2) FUSED(3) FUSED(4)
        FUSED(5) FUSED(6) FUSED(7) FUSED(8) FUSED(9)
    } else {
        FUSEDC(0) FUSEDC(1) FUSEDC(2) FUSEDC(3) FUSEDC(4)
        FUSEDC(5) FUSEDC(6) FUSEDC(7) FUSEDC(8) FUSEDC(9)
    }

    // ---- epilogue: both subtiles; C/D col=pl, row=s*4+r ----
    {
        const int tc0 = T0 + w * 16 + pl;
        #pragma unroll
        for (int ot = 0; ot < 4; ++ot) {
            const f32x4 aA = (ot==0)?accA0:(ot==1)?accA1:(ot==2)?accA2:accA3;
            const f32x4 aB = (ot==0)?accB0:(ot==1)?accB1:(ot==2)?accB2:accB3;
            #pragma unroll
            for (int r = 0; r < 4; ++r) {
                int o = ot * 16 + s * 4 + r;
                float bvv = bias[o];
                float* op = out + ((size_t)(b * COUT + o)) * LEN + tc0;
                op[0]  = aA[r] + bvv;
                op[64] = aB[r] + bvv;
            }
        }
    }
#undef FUSEDC
#undef CHECKED1
#undef FUSED
#undef MFMA8
#undef GATHS
#undef GATHF
#undef LERPW
#undef STAGE_WRITE
#undef STAGE_LOAD
}

extern "C" void kernel_launch(void* const* d_in, const int* in_sizes, int n_in,
                              void* d_out, int out_size, void* d_ws, size_t ws_size,
                              hipStream_t stream) {
    const float* x    = (const float*)d_in[0];
    const float* offs = (const float*)d_in[1];
    const float* w    = (const float*)d_in[2];
    const float* bias = (const float*)d_in[3];
    float* out = (float*)d_out;
    unsigned short* wf = (unsigned short*)d_ws;   // 40960 B

    wfrag_kernel<<<80, 256, 0, stream>>>(w, wf);
    deform_mfma_kernel<<<BATCH * (LEN / TTB), 256, 0, stream>>>(x, offs, wf, bias, out);
}